// Round 3
// baseline (1661.544 us; speedup 1.0000x reference)
//
#include <hip/hip_runtime.h>
#include <hip/hip_cooperative_groups.h>

namespace cg = cooperative_groups;

#define N_NODES 10000
#define F_IN    256
#define H1      128
#define H2      64
#define NEDGE   320000
#define M_TOT   (NEDGE + N_NODES)

#define NB 512          // cooperative grid: 2 blocks/CU guaranteed by launch_bounds
#define NT 256

typedef __attribute__((ext_vector_type(8))) short          s16v8;  // 8 bf16 (4 VGPRs)
typedef __attribute__((ext_vector_type(8))) unsigned short u16v8;
typedef __attribute__((ext_vector_type(4))) float          f32v4;

// ---------------------------------------------------------------- mega prep
// All of {init, count, scan, scatter, gemm1, agg1, gemm23, agg2} in ONE
// cooperative kernel with grid.sync() phase boundaries. Rationale: bottom-up
// kernel cost sums to ~150-200us but measured total is ~677us -> the residual
// is per-dispatch serialization; 9 launches -> 2.
__global__ __launch_bounds__(NT, 2) void k_mega(
    const float* __restrict__ x,  const int* __restrict__ ei, const float* __restrict__ w,
    const float* __restrict__ W1, const float* __restrict__ b1,
    const float* __restrict__ W2, const float* __restrict__ b2,
    const float* __restrict__ W3, const float* __restrict__ b3,
    float* deg, int* cnt, int* ptr, int* cur, int* part,
    int* src, float* wgt, float* hw, float* h1, float* t2, float* t3,
    float* mu, float* lv)
{
    cg::grid_group grid = cg::this_grid();
    __shared__ float smem[16 * F_IN];          // 16 KB staging, reused per phase
    __shared__ int   wsum[8];
    int tid  = threadIdx.x;
    int bid  = blockIdx.x;
    int gtid = bid * NT + tid;                 // 0..131071

    // ---- phase A: init deg/cnt (self-loop) + gemm1 hw = x@W1 (independent) ----
    if (gtid < N_NODES) { deg[gtid] = 1.0f; cnt[gtid] = 1; }
    for (int tile = bid; tile < N_NODES / 16; tile += NB) {
        int i0 = tile * 16;
        __syncthreads();                       // prior tile's readers done
        const float4* xsrc = (const float4*)(x + (size_t)i0 * F_IN);
        float4* xd = (float4*)smem;
#pragma unroll
        for (int j = 0; j < 4; j++) xd[tid + j * 256] = xsrc[tid + j * 256];
        __syncthreads();
        int col = tid & 127, half = tid >> 7;
        const float* xrow = smem + (half * 8) * F_IN;
        float acc[8] = {0, 0, 0, 0, 0, 0, 0, 0};
        for (int k = 0; k < F_IN; k += 4) {
            float w0 = W1[(k + 0) * H1 + col];
            float w1 = W1[(k + 1) * H1 + col];
            float w2 = W1[(k + 2) * H1 + col];
            float w3 = W1[(k + 3) * H1 + col];
#pragma unroll
            for (int r = 0; r < 8; r++) {
                float4 xv = *(const float4*)&xrow[r * F_IN + k];   // wave-uniform bcast
                acc[r] += xv.x * w0 + xv.y * w1 + xv.z * w2 + xv.w * w3;
            }
        }
#pragma unroll
        for (int r = 0; r < 8; r++)
            hw[(size_t)(i0 + half * 8 + r) * H1 + col] = acc[r];
    }
    __threadfence();
    grid.sync();

    // ---- phase B: degree count ----
    for (int e = gtid; e < NEDGE; e += NB * NT) {
        int c = ei[NEDGE + e];
        atomicAdd(&deg[c], w[e]);
        atomicAdd(&cnt[c], 1);
    }
    __threadfence();
    grid.sync();

    // ---- phase C: scan step 1 — blocks 0..39, 1 node/thread, block scan ----
    int myExcl = 0;                            // survives across grid syncs in regs
    if (bid < 40) {
        int v = (gtid < N_NODES) ? cnt[gtid] : 0;
        int lane = tid & 63, wv = tid >> 6;
        int xi = v;                            // wave inclusive scan
#pragma unroll
        for (int d = 1; d < 64; d <<= 1) {
            int y = __shfl_up(xi, d, 64);
            if (lane >= d) xi += y;
        }
        if (lane == 63) wsum[wv] = xi;
        __syncthreads();
        if (tid == 0) {
            int s = 0;
#pragma unroll
            for (int i2 = 0; i2 < 4; i2++) { int tt = wsum[i2]; wsum[i2] = s; s += tt; }
            wsum[7] = s;
        }
        __syncthreads();
        myExcl = xi - v + wsum[wv];
        if (tid == 0) part[bid] = wsum[7];
    }
    __threadfence();
    grid.sync();

    // ---- phase D: scan step 2 — block 0 wave 0 scans the 40 partials ----
    if (bid == 0 && tid < 64) {
        int v = (tid < 40) ? part[tid] : 0;
        int xi = v;
#pragma unroll
        for (int d = 1; d < 64; d <<= 1) {
            int y = __shfl_up(xi, d, 64);
            if (tid >= d) xi += y;
        }
        if (tid < 40) part[tid] = xi - v;      // exclusive block offset
    }
    __threadfence();
    grid.sync();

    // ---- phase E: scan step 3 — emit ptr/cur ----
    if (bid < 40 && gtid < N_NODES) {
        int p = part[bid] + myExcl;
        ptr[gtid] = p; cur[gtid] = p;
    }
    if (gtid == 0) ptr[N_NODES] = M_TOT;       // total is data-independent
    __threadfence();
    grid.sync();

    // ---- phase F: scatter into CSR-by-col (rsqrt folded in) ----
    for (int t = gtid; t < M_TOT; t += NB * NT) {
        int r, c; float nw;
        if (t < NEDGE) {
            r = ei[t]; c = ei[NEDGE + t];
            nw = rsqrtf(deg[r]) * w[t] * rsqrtf(deg[c]);
        } else {
            r = c = t - NEDGE;
            float d = rsqrtf(deg[r]);
            nw = d * d;
        }
        int pos = atomicAdd(&cur[c], 1);
        src[pos] = r; wgt[pos] = nw;
    }
    __threadfence();
    grid.sync();

    // ---- phase G: agg1  h1 = relu(segsum + b1), 2 nodes per chunk ----
    for (int ch = bid; ch < N_NODES / 2; ch += NB) {
        int i = ch * 2 + (tid >> 7);           // per-wave uniform node
        int f = tid & 127;
        int jb = ptr[i], je = ptr[i + 1];
        float acc = b1[f];
        for (int j = jb; j < je; j++)
            acc += wgt[j] * hw[(size_t)src[j] * H1 + f];
        h1[(size_t)i * H1 + f] = fmaxf(acc, 0.0f);
    }
    __threadfence();
    grid.sync();

    // ---- phase H: gemm23  t2 = h1@W2, t3 = h1@W3 ----
    for (int tile = bid; tile < N_NODES / 16; tile += NB) {
        int i0 = tile * 16;
        __syncthreads();
        const float4* hsrc = (const float4*)(h1 + (size_t)i0 * H1);
        float4* hd = (float4*)smem;
#pragma unroll
        for (int j = 0; j < 2; j++) hd[tid + j * 256] = hsrc[tid + j * 256];
        __syncthreads();
        int f = tid & 63, sel = (tid >> 6) & 1, half = tid >> 7;  // wave-uniform sel
        const float* W = sel ? W3 : W2;
        const float* hrow = smem + (half * 8) * H1;
        float acc[8] = {0, 0, 0, 0, 0, 0, 0, 0};
        for (int k = 0; k < H1; k += 4) {
            float w0 = W[(k + 0) * H2 + f];
            float w1 = W[(k + 1) * H2 + f];
            float w2 = W[(k + 2) * H2 + f];
            float w3 = W[(k + 3) * H2 + f];
#pragma unroll
            for (int r = 0; r < 8; r++) {
                float4 hv = *(const float4*)&hrow[r * H1 + k];
                acc[r] += hv.x * w0 + hv.y * w1 + hv.z * w2 + hv.w * w3;
            }
        }
        float* o = sel ? t3 : t2;
#pragma unroll
        for (int r = 0; r < 8; r++)
            o[(size_t)(i0 + half * 8 + r) * H2 + f] = acc[r];
    }
    __threadfence();
    grid.sync();

    // ---- phase I: agg2  mu/logvar ----
    for (int ch = bid; ch < N_NODES / 2; ch += NB) {
        int i = ch * 2 + (tid >> 7);
        int f = tid & 63, sel = (tid >> 6) & 1;
        const float* tin = sel ? t3 : t2;
        float acc = sel ? b3[f] : b2[f];
        int jb = ptr[i], je = ptr[i + 1];
        for (int j = jb; j < je; j++)
            acc += wgt[j] * tin[(size_t)src[j] * H2 + f];
        float* o = sel ? lv : mu;
        o[(size_t)i * H2 + f] = acc;
    }
}

// ---------------------------------------------------------------- adj = z z^T
// (unchanged from round 2 — verified correct: MFMA 3-way bf16 split, 128B-row
// XOR swizzle, upper-triangle + mirror stores)
__global__ __launch_bounds__(256, 1) void k_adj(const float* __restrict__ z,
                                                float* __restrict__ adj) {
    if (blockIdx.x < blockIdx.y) return;          // symmetry: upper triangle only
    __shared__ __align__(16) unsigned short PAs[128 * 64];
    __shared__ __align__(16) unsigned short PBs[128 * 64];
    __shared__ __align__(16) unsigned short PLs[128 * 64];
    int tid = threadIdx.x;
    int rowBase = blockIdx.y * 128, colBase = blockIdx.x * 128;
    bool diag = (blockIdx.x == blockIdx.y);

    int lane = tid & 63;
    int wv   = tid >> 6;
    int wr = (wv >> 1) * 64;               // wave's output quadrant
    int wc = (wv & 1) * 64;
    int lrow = lane & 15;
    int lk   = lane >> 4;                  // k-chunk (8 bf16) within 32-k stage

    int sr   = tid & 127;
    int isB  = tid >> 7;
    int gbase = (isB ? colBase : rowBase) + sr;
    bool ok = gbase < N_NODES;
    const float* srcp = z + (size_t)gbase * 64;
    unsigned short* PH = isB ? PBs : PAs;
    int lslotBase = isB ? 4 : 0;           // Al in slots 0-3 of PL, Bl in 4-7
    int rb7 = sr & 7;

    auto stage = [&](int s) {
#pragma unroll
        for (int g = 0; g < 4; g++) {      // 4 chunks of 8 k per 32-k stage
            float v[8];
            if (ok) {
                float4 a = *(const float4*)(srcp + s * 32 + g * 8);
                float4 b = *(const float4*)(srcp + s * 32 + g * 8 + 4);
                v[0] = a.x; v[1] = a.y; v[2] = a.z; v[3] = a.w;
                v[4] = b.x; v[5] = b.y; v[6] = b.z; v[7] = b.w;
            } else {
#pragma unroll
                for (int q = 0; q < 8; q++) v[q] = 0.0f;
            }
            u16v8 hv, mv, lv8;
#pragma unroll
            for (int q = 0; q < 8; q++) {
                float xv = v[q];
                unsigned hu = __float_as_uint(xv) & 0xffff0000u;       // h = trunc bf16
                float r1 = xv - __uint_as_float(hu);
                unsigned mu2 = __float_as_uint(r1) & 0xffff0000u;      // m
                float r2 = r1 - __uint_as_float(mu2);
                unsigned lu = __float_as_uint(r2) & 0xffff0000u;       // l
                hv[q]  = (unsigned short)(hu >> 16);
                mv[q]  = (unsigned short)(mu2 >> 16);
                lv8[q] = (unsigned short)(lu >> 16);
            }
            int base = sr * 64;
            *reinterpret_cast<u16v8*>(PH  + base + ((g              ^ rb7) * 8)) = hv;
            *reinterpret_cast<u16v8*>(PH  + base + (((4 + g)        ^ rb7) * 8)) = mv;
            *reinterpret_cast<u16v8*>(PLs + base + (((lslotBase + g) ^ rb7) * 8)) = lv8;
        }
    };

    f32v4 acc[4][4];
#pragma unroll
    for (int i = 0; i < 4; i++)
#pragma unroll
        for (int j = 0; j < 4; j++) acc[i][j] = (f32v4)0.0f;

    s16v8 a0[4], a1[4], a2[4], b0[4], b1[4], b2[4];

#define LOADFRAGS()                                                        \
    {                                                                      \
        _Pragma("unroll")                                                  \
        for (int fq = 0; fq < 4; fq++) {                                   \
            int ra = wr + fq * 16 + lrow;                                  \
            int r7 = ra & 7;                                               \
            int ia = ra * 64;                                              \
            a0[fq] = *reinterpret_cast<const s16v8*>(&PAs[ia + ((lk       ^ r7) * 8)]); \
            a1[fq] = *reinterpret_cast<const s16v8*>(&PAs[ia + (((4 + lk) ^ r7) * 8)]); \
            a2[fq] = *reinterpret_cast<const s16v8*>(&PLs[ia + ((lk       ^ r7) * 8)]); \
            int rb = wc + fq * 16 + lrow;                                  \
            int q7 = rb & 7;                                               \
            int ib = rb * 64;                                              \
            b0[fq] = *reinterpret_cast<const s16v8*>(&PBs[ib + ((lk       ^ q7) * 8)]); \
            b1[fq] = *reinterpret_cast<const s16v8*>(&PBs[ib + (((4 + lk) ^ q7) * 8)]); \
            b2[fq] = *reinterpret_cast<const s16v8*>(&PLs[ib + (((4 + lk) ^ q7) * 8)]); \
        }                                                                  \
    }

#define MFMAS()                                                            \
    {                                                                      \
        _Pragma("unroll")                                                  \
        for (int i = 0; i < 4; i++) {                                      \
            _Pragma("unroll")                                              \
            for (int j = 0; j < 4; j++) {                                  \
                f32v4 c = acc[i][j];                                       \
                c = __builtin_amdgcn_mfma_f32_16x16x32_bf16(a0[i], b0[j], c, 0, 0, 0); \
                c = __builtin_amdgcn_mfma_f32_16x16x32_bf16(a0[i], b1[j], c, 0, 0, 0); \
                c = __builtin_amdgcn_mfma_f32_16x16x32_bf16(a1[i], b0[j], c, 0, 0, 0); \
                c = __builtin_amdgcn_mfma_f32_16x16x32_bf16(a0[i], b2[j], c, 0, 0, 0); \
                c = __builtin_amdgcn_mfma_f32_16x16x32_bf16(a2[i], b0[j], c, 0, 0, 0); \
                c = __builtin_amdgcn_mfma_f32_16x16x32_bf16(a1[i], b1[j], c, 0, 0, 0); \
                acc[i][j] = c;                                             \
            }                                                              \
        }                                                                  \
    }

    stage(0);
    __syncthreads();
    LOADFRAGS();                // k-stage 0 frags -> regs
    __syncthreads();            // everyone done reading stage-0 LDS
    stage(1);                   // global loads overlap with MFMAs below
    MFMAS();                    // k 0..31
    __syncthreads();            // stage-1 writes visible
    LOADFRAGS();                // k-stage 1 frags
    MFMAS();                    // k 32..63

#undef LOADFRAGS
#undef MFMAS

#pragma unroll
    for (int i = 0; i < 4; i++) {
        int r0 = rowBase + wr + i * 16 + lk * 4;
#pragma unroll
        for (int j = 0; j < 4; j++) {
            int cg = colBase + wc + j * 16 + lrow;
            if (cg < N_NODES) {
#pragma unroll
                for (int v = 0; v < 4; v++) {
                    int rg = r0 + v;
                    if (rg < N_NODES)
                        adj[(size_t)rg * N_NODES + cg] = acc[i][j][v];
                }
                if (!diag)
                    *(float4*)&adj[(size_t)cg * N_NODES + r0] =
                        make_float4(acc[i][j][0], acc[i][j][1], acc[i][j][2], acc[i][j][3]);
            }
        }
    }
}

// ---------------------------------------------------------------- launch

extern "C" void kernel_launch(void* const* d_in, const int* in_sizes, int n_in,
                              void* d_out, int out_size, void* d_ws, size_t ws_size,
                              hipStream_t stream) {
    const float* x  = (const float*)d_in[0];
    const int*   ei = (const int*)d_in[1];      // harness passes ints as int32
    const float* w  = (const float*)d_in[2];
    const float* W1 = (const float*)d_in[3];
    const float* b1 = (const float*)d_in[4];
    const float* W2 = (const float*)d_in[5];
    const float* b2 = (const float*)d_in[6];
    const float* W3 = (const float*)d_in[7];
    const float* b3 = (const float*)d_in[8];

    float* out = (float*)d_out;
    float* adj = out;
    float* mu  = out + (size_t)N_NODES * N_NODES;
    float* lv  = mu + (size_t)N_NODES * H2;

    // Scratch in the tail of the adj region (offset 320 MB of the 400 MB adj
    // block). Dead before k_adj overwrites it; written before read every call.
    float* ws  = out + 80000000;
    float* deg = ws;                        // 10240 floats
    int*   cnt = (int*)(ws + 10240);        // 10240
    int*   ptr = (int*)(ws + 20480);        // 10240 (10001 used)
    int*   cur = (int*)(ws + 30720);        // 10240
    int*   src = (int*)(ws + 40960);        // 330240
    float* wgt = ws + 371200;               // 330240
    float* hw  = ws + 701440;               // 1,280,000
    float* h1  = ws + 1981440;              // 1,280,000
    float* t2  = ws + 3261440;              // 640,000
    float* t3  = ws + 3901440;              // 640,000
    int*   part = (int*)(ws + 4541440);     // 512

    void* args[] = {
        (void*)&x,  (void*)&ei, (void*)&w,
        (void*)&W1, (void*)&b1, (void*)&W2, (void*)&b2, (void*)&W3, (void*)&b3,
        (void*)&deg, (void*)&cnt, (void*)&ptr, (void*)&cur, (void*)&part,
        (void*)&src, (void*)&wgt, (void*)&hw, (void*)&h1, (void*)&t2, (void*)&t3,
        (void*)&mu, (void*)&lv };
    hipLaunchCooperativeKernel((const void*)k_mega, dim3(NB), dim3(NT), args, 0, stream);

    dim3 g((N_NODES + 127) / 128, (N_NODES + 127) / 128);
    hipLaunchKernelGGL(k_adj, g, dim3(256), 0, stream, mu, adj);
}